// Round 5
// baseline (2489.236 us; speedup 1.0000x reference)
//
#include <hip/hip_runtime.h>

#define B_    8
#define N_    8192
#define M_    2000
#define K_    16
#define C1_   128
#define C2_   256
#define OUT_  100
#define SUBP_ 2048   // padded per-batch pitch for subsampled points (KNN2 candidates)

// ---------------------------------------------------------------- prep: coords -> float4(x,y,z,|p|^2); pad sub4 sentinels
__global__ __launch_bounds__(256) void prep_kernel(const float* __restrict__ x,
                                                   float4* __restrict__ coords4,
                                                   float4* __restrict__ sub4) {
    int i = blockIdx.x * 256 + threadIdx.x;
    if (i < B_ * N_) {
        float xx = x[i*3+0], yy = x[i*3+1], zz = x[i*3+2];
        float ss = fmaf(zz, zz, fmaf(yy, yy, xx*xx));   // ((x^2+y^2)+z^2)
        coords4[i] = make_float4(xx, yy, zz, ss);
    }
    if (i < B_ * (SUBP_ - M_)) {   // sentinel pads: huge distance, never selected
        int b = i / (SUBP_ - M_), j = i % (SUBP_ - M_);
        sub4[b*SUBP_ + M_ + j] = make_float4(1e15f, 1e15f, 1e15f, 3e30f);
    }
}

// ---------------------------------------------------------------- FPS v6: 512 threads (2 waves/SIMD) + packed-fp32 inner loop
// v5 post-mortem: 256 threads lost the co-wave that hides the ~400cy serial tail
// (occupancy 0.38), AND 16 v2f pairs/thread needed ~170 VGPR vs 132 allocated ->
// spill shuffling in the hot loop. v6 keeps v5's packed math but at v4's shell:
// 512 threads, 8 pairs/thread (~110 VGPR, no spill), 2 waves/SIMD for tail hiding.
//  - v_pk_{add,mul,fma}_f32: 2 points/inst (bit-exact: a+(-b)==a-b, pk rounding
//    == scalar, same fmaf association as ref)
//  - incremental strict-> argmax keeps earliest max = smallest orig idx = ref ties
#define FPS_T 512
#define FPS_PP 8    // float2 point-pairs per thread: 8 pairs = 16 points

typedef float v2f __attribute__((ext_vector_type(2)));

__device__ __forceinline__ v2f pk_add(v2f a, v2f b) {
    v2f d; asm("v_pk_add_f32 %0, %1, %2" : "=v"(d) : "v"(a), "v"(b)); return d;
}
__device__ __forceinline__ v2f pk_mul(v2f a, v2f b) {
    v2f d; asm("v_pk_mul_f32 %0, %1, %2" : "=v"(d) : "v"(a), "v"(b)); return d;
}
__device__ __forceinline__ v2f pk_fma(v2f a, v2f b, v2f c) {
    v2f d; asm("v_pk_fma_f32 %0, %1, %2, %3" : "=v"(d) : "v"(a), "v"(b), "v"(c)); return d;
}

__device__ __forceinline__ unsigned long long umax64(unsigned long long a, unsigned long long b) {
    return a > b ? a : b;
}

// one stage of wave-max on a u64 key via DPP on both halves (identity 0: keys are non-negative)
template<int CTRL>
__device__ __forceinline__ unsigned long long dpp_max_u64(unsigned long long v) {
    int lo = __builtin_amdgcn_update_dpp(0, (int)(unsigned)(v & 0xFFFFFFFFull), CTRL, 0xF, 0xF, true);
    int hi = __builtin_amdgcn_update_dpp(0, (int)(v >> 32),                     CTRL, 0xF, 0xF, true);
    unsigned long long o = ((unsigned long long)(unsigned)hi << 32) | (unsigned)lo;
    return umax64(v, o);
}

__global__ __launch_bounds__(FPS_T, 1) void fps_kernel(const float4* __restrict__ coords4,
                                                       float4* __restrict__ sub4) {
    int b = blockIdx.x;
    int t = threadIdx.x;
    int w = t >> 6, lane = t & 63;
    const float4* C = coords4 + b * N_;

    __shared__ float4 Clds[N_];                              // 128 KB coords mirror (winner broadcast)
    __shared__ __align__(16) unsigned long long wkey[2][8];  // per-wave max keys, parity double-buffered

    v2f px_[FPS_PP], py_[FPS_PP], pz_[FPS_PP], mind[FPS_PP];
    unsigned inva_[FPS_PP], invb_[FPS_PP];
#pragma unroll
    for (int j = 0; j < FPS_PP; ++j) {
        int ia = t + (2*j)*FPS_T, ic = t + (2*j+1)*FPS_T;    // ascending orig idx in scan order
        float4 pa = C[ia], pb = C[ic];
        Clds[ia] = pa; Clds[ic] = pb;
        px_[j].x = pa.x; px_[j].y = pb.x;
        py_[j].x = pa.y; py_[j].y = pb.y;
        pz_[j].x = pa.z; pz_[j].y = pb.z;
        mind[j].x = 1e30f; mind[j].y = 1e30f;
        inva_[j] = 0xFFFFFFFFu - (unsigned)ia;               // tie -> smaller orig idx == larger inv
        invb_[j] = 0xFFFFFFFFu - (unsigned)ic;
    }
    float4 P0 = C[0];                                        // first pick = original index 0
    if (t == 0) sub4[b*SUBP_] = P0;
    v2f nPx2 = {-P0.x, -P0.x}, nPy2 = {-P0.y, -P0.y}, nPz2 = {-P0.z, -P0.z};
    __syncthreads();

    for (int i = 1; i < M_; ++i) {
        float runA = -3.4e38f, runB = -3.4e38f;
        unsigned ibA = 0u, ibB = 0u;
#pragma unroll
        for (int j = 0; j < FPS_PP; ++j) {
            v2f dx = pk_add(px_[j], nPx2);                   // px - Px (exact: a+(-b) == a-b)
            v2f dy = pk_add(py_[j], nPy2);
            v2f dz = pk_add(pz_[j], nPz2);
            v2f d2 = pk_fma(dz, dz, pk_fma(dy, dy, pk_mul(dx, dx)));  // matches ref association
            float m0 = fminf(mind[j].x, d2.x);
            float m1 = fminf(mind[j].y, d2.y);
            mind[j].x = m0; mind[j].y = m1;
            ibA = (m0 > runA) ? inva_[j] : ibA;              // strict >: earliest max kept (= ref tie)
            runA = fmaxf(runA, m0);
            ibB = (m1 > runB) ? invb_[j] : ibB;
            runB = fmaxf(runB, m1);
        }
        float runmax = fmaxf(runA, runB);
        // combine halves: equal values -> larger inv (smaller orig idx)
        unsigned ib = (runB > runA) ? ibB : ((runB == runA) ? (ibA > ibB ? ibA : ibB) : ibA);
        unsigned long long best = ((unsigned long long)__float_as_uint(runmax) << 32)
                                | (unsigned long long)ib;
        // wave max into lane 63: row_shr 1/2/4/8 then row_bcast 15/31 (all VALU)
        best = dpp_max_u64<0x111>(best);
        best = dpp_max_u64<0x112>(best);
        best = dpp_max_u64<0x114>(best);
        best = dpp_max_u64<0x118>(best);
        best = dpp_max_u64<0x142>(best);
        best = dpp_max_u64<0x143>(best);
        if (lane == 63) wkey[i & 1][w] = best;
        __syncthreads();
        const ulonglong2* wk2 = (const ulonglong2*)wkey[i & 1];
        ulonglong2 q0 = wk2[0], q1 = wk2[1], q2 = wk2[2], q3 = wk2[3];
        unsigned long long gk = umax64(umax64(umax64(q0.x, q0.y), umax64(q1.x, q1.y)),
                                       umax64(umax64(q2.x, q2.y), umax64(q3.x, q3.y)));
        int last = (int)(0xFFFFFFFFu - (unsigned)(gk & 0xFFFFFFFFull));
        float4 P4 = Clds[last];                              // broadcast LDS read (w = |p|^2 intact)
        nPx2.x = -P4.x; nPx2.y = -P4.x;
        nPy2.x = -P4.y; nPy2.y = -P4.y;
        nPz2.x = -P4.z; nPz2.y = -P4.z;
        if (t == 0) sub4[b*SUBP_ + i] = P4;
    }
}

// ---------------------------------------------------------------- KNN: 1 wave per query, exact top-16 (set semantics)
// Pass 1: branchless lane-local sorted-16 of values only (15 CE bubble per candidate).
// Merge:  k-way merge of 64 sorted heads -> T = exact 16th smallest distance.
// Pass 2: ballot-collect indices with d<T, then earliest-index ties d==T (matches lax.top_k stability).
template<int NCH, int PITCH>
__global__ __launch_bounds__(256) void knn_kernel(const float4* __restrict__ cand,
                                                  const float4* __restrict__ qarr,
                                                  int* __restrict__ outIdx) {
    int lane = threadIdx.x & 63;
    int q = blockIdx.x * 4 + (threadIdx.x >> 6);
    int b = q / M_, m = q % M_;
    const float4* Cb = cand + b * PITCH;
    float4 Q = qarr[b * SUBP_ + m];

    float v[16];
#pragma unroll
    for (int tt = 0; tt < 16; ++tt) v[tt] = 3.4e38f;

#pragma unroll 2
    for (int j = 0; j < NCH; ++j) {
        float4 c = Cb[j*64 + lane];
        float dot = fmaf(c.z, Q.z, fmaf(c.y, Q.y, c.x * Q.x));
        float d = fmaf(-2.0f, dot, Q.w + c.w);   // == (qq+ss) - 2*dot, single rounding
        v[15] = fminf(v[15], d);
#pragma unroll
        for (int tt = 15; tt >= 1; --tt) {       // restore sortedness: bubble toward 0
            float lo = fminf(v[tt-1], v[tt]);
            float hi = fmaxf(v[tt-1], v[tt]);
            v[tt-1] = lo; v[tt] = hi;
        }
    }

    float T = 0.0f;
    for (int r = 0; r < 16; ++r) {               // extract global min 16 times (one entry per round)
        float g = v[0];
#pragma unroll
        for (int s = 1; s < 64; s <<= 1) g = fminf(g, __shfl_xor(g, s, 64));
        unsigned long long mk = __ballot(v[0] == g);
        int fl = __ffsll(mk) - 1;                // exactly one lane consumes (value ties resolved)
        if (lane == fl) {
#pragma unroll
            for (int tt = 0; tt < 15; ++tt) v[tt] = v[tt+1];
            v[15] = 3.4e38f;
        }
        T = g;
    }

    unsigned long long mlt = (1ull << lane) - 1ull;
    int base = q * K_;
    int cnt = 0;
    for (int j = 0; j < NCH; ++j) {              // all strictly-closer candidates (<= 15 of them)
        float4 c = Cb[j*64 + lane];
        float dot = fmaf(c.z, Q.z, fmaf(c.y, Q.y, c.x * Q.x));
        float d = fmaf(-2.0f, dot, Q.w + c.w);
        bool lt = d < T;
        unsigned long long m1 = __ballot(lt);
        if (lt) outIdx[base + cnt + __popcll(m1 & mlt)] = j*64 + lane;
        cnt += __popcll(m1);
    }
    int rem = K_ - cnt;                          // >= 1 (T itself); fill with earliest-index ties
    for (int j = 0; j < NCH && rem > 0; ++j) {
        float4 c = Cb[j*64 + lane];
        float dot = fmaf(c.z, Q.z, fmaf(c.y, Q.y, c.x * Q.x));
        float d = fmaf(-2.0f, dot, Q.w + c.w);
        bool eq = (d == T);
        unsigned long long m2 = __ballot(eq);
        int bef = __popcll(m2 & mlt);
        if (eq && bef < rem) outIdx[base + cnt + bef] = j*64 + lane;
        int take = __popcll(m2); if (take > rem) take = rem;
        cnt += take; rem -= take;
    }
}

// ---------------------------------------------------------------- layer 1: feats=[rel(3), ngh(3)] x W1[6,128], relu, max over k
__global__ __launch_bounds__(128) void layer1_kernel(const float4* __restrict__ coords4,
        const float4* __restrict__ sub4, const int* __restrict__ idx1,
        const float* __restrict__ W1, const float* __restrict__ b1,
        float* __restrict__ f1) {
    int q = blockIdx.x;
    int b = q / M_, m = q % M_;
    int c = threadIdx.x;
    __shared__ float4 ngh[K_];
    if (c < K_) ngh[c] = coords4[b*N_ + idx1[q*K_ + c]];
    __syncthreads();
    float4 Q = sub4[b*SUBP_ + m];
    float w0 = W1[c],        w1 = W1[C1_ + c],   w2 = W1[2*C1_ + c];
    float w3 = W1[3*C1_ + c], w4 = W1[4*C1_ + c], w5 = W1[5*C1_ + c];
    float bias = b1[c];
    float mx = -3.4e38f;
#pragma unroll
    for (int k = 0; k < K_; ++k) {
        float4 n = ngh[k];
        float rx = n.x - Q.x, ry = n.y - Q.y, rz = n.z - Q.z;
        float s = rx*w0; s = fmaf(ry,w1,s); s = fmaf(rz,w2,s);
        s = fmaf(n.x,w3,s); s = fmaf(n.y,w4,s); s = fmaf(n.z,w5,s);
        s += bias;
        s = fmaxf(s, 0.0f);
        mx = fmaxf(mx, s);
    }
    f1[q*C1_ + c] = mx;
}

// ---------------------------------------------------------------- layer 2: feats=[rel(3), fg(128)] x W2[131,256], relu, max over k
#define FPAD 20   // row pitch (floats): 16B-aligned rows, odd-ish banking for staging
__global__ __launch_bounds__(64) void layer2_kernel(const float4* __restrict__ sub4,
        const float* __restrict__ f1, const int* __restrict__ idx2,
        const float* __restrict__ W2, const float* __restrict__ b2,
        float* __restrict__ f2) {
    int q = blockIdx.x;
    int b = q / M_, m = q % M_;
    int t = threadIdx.x;
    __shared__ __align__(16) float feat[(3 + C1_) * FPAD];  // feat[f][k], k=0..15
    __shared__ int nidx[K_];
    float4 Q = sub4[b*SUBP_ + m];
    if (t < K_) {
        int ik = idx2[q*K_ + t];
        nidx[t] = ik;
        float4 n = sub4[b*SUBP_ + ik];
        feat[0*FPAD + t] = n.x - Q.x;
        feat[1*FPAD + t] = n.y - Q.y;
        feat[2*FPAD + t] = n.z - Q.z;
    }
    __syncthreads();
    for (int e = t; e < K_ * C1_; e += 64) {    // stage gathered f1 rows: feat[3+cc][k]
        int k = e >> 7, cc = e & 127;
        feat[(3 + cc)*FPAD + k] = f1[(b*M_ + nidx[k])*C1_ + cc];
    }
    __syncthreads();

    float acc[K_][4];
#pragma unroll
    for (int k = 0; k < K_; ++k) { acc[k][0]=0.f; acc[k][1]=0.f; acc[k][2]=0.f; acc[k][3]=0.f; }
    int c0 = t * 4;                              // 4 channels per thread, 64 threads = 256 ch
    for (int f = 0; f < 3 + C1_; ++f) {
        float4 w  = *(const float4*)(W2 + f*C2_ + c0);
        const float* row = feat + f*FPAD;
        float4 g0 = *(const float4*)(row + 0);
        float4 g1 = *(const float4*)(row + 4);
        float4 g2 = *(const float4*)(row + 8);
        float4 g3 = *(const float4*)(row + 12);
        float gk[16] = {g0.x,g0.y,g0.z,g0.w, g1.x,g1.y,g1.z,g1.w,
                        g2.x,g2.y,g2.z,g2.w, g3.x,g3.y,g3.z,g3.w};
#pragma unroll
        for (int k = 0; k < K_; ++k) {
            acc[k][0] = fmaf(gk[k], w.x, acc[k][0]);
            acc[k][1] = fmaf(gk[k], w.y, acc[k][1]);
            acc[k][2] = fmaf(gk[k], w.z, acc[k][2]);
            acc[k][3] = fmaf(gk[k], w.w, acc[k][3]);
        }
    }
    float4 bb = *(const float4*)(b2 + c0);
    float mx0 = -3.4e38f, mx1 = -3.4e38f, mx2 = -3.4e38f, mx3 = -3.4e38f;
#pragma unroll
    for (int k = 0; k < K_; ++k) {
        float h0 = fmaxf(acc[k][0] + bb.x, 0.0f);
        float h1 = fmaxf(acc[k][1] + bb.y, 0.0f);
        float h2 = fmaxf(acc[k][2] + bb.z, 0.0f);
        float h3 = fmaxf(acc[k][3] + bb.w, 0.0f);
        mx0 = fmaxf(mx0, h0); mx1 = fmaxf(mx1, h1);
        mx2 = fmaxf(mx2, h2); mx3 = fmaxf(mx3, h3);
    }
    *(float4*)(f2 + q*C2_ + c0) = make_float4(mx0, mx1, mx2, mx3);
}

// ---------------------------------------------------------------- fused adaptive max+avg pool
__global__ __launch_bounds__(256) void pool_kernel(const float* __restrict__ f2,
                                                   float* __restrict__ out) {
    int bo = blockIdx.x;
    int b = bo / OUT_, o = bo % OUT_;
    int c = threadIdx.x;
    float mx = -3.4e38f, sm = 0.0f;
#pragma unroll
    for (int w = 0; w < M_/OUT_; ++w) {
        float v = f2[(b*M_ + o*(M_/OUT_) + w)*C2_ + c];
        mx = fmaxf(mx, v);
        sm += v;
    }
    out[(b*C2_ + c)*OUT_ + o] = mx + sm / (float)(M_/OUT_);
}

// ---------------------------------------------------------------- launch
extern "C" void kernel_launch(void* const* d_in, const int* in_sizes, int n_in,
                              void* d_out, int out_size, void* d_ws, size_t ws_size,
                              hipStream_t stream) {
    const float* x  = (const float*)d_in[0];
    const float* W1 = (const float*)d_in[1];
    const float* b1 = (const float*)d_in[2];
    const float* W2 = (const float*)d_in[3];
    const float* b2 = (const float*)d_in[4];
    float* out = (float*)d_out;

    char* ws = (char*)d_ws;
    size_t off = 0;
    auto alloc = [&](size_t bytes) {
        void* p = ws + off;
        off += (bytes + 255) & ~(size_t)255;
        return p;
    };
    float4* coords4 = (float4*)alloc((size_t)B_*N_*sizeof(float4));     // 2 MB
    float4* sub4    = (float4*)alloc((size_t)B_*SUBP_*sizeof(float4));  // 256 KB
    int*    idx1    = (int*)  alloc((size_t)B_*M_*K_*sizeof(int));      // 2 MB
    int*    idx2    = (int*)  alloc((size_t)B_*M_*K_*sizeof(int));      // 2 MB
    float*  f1      = (float*)alloc((size_t)B_*M_*C1_*sizeof(float));   // 8 MB
    float*  f2      = (float*)alloc((size_t)B_*M_*C2_*sizeof(float));   // 16 MB

    prep_kernel<<<(B_*N_ + 255)/256, 256, 0, stream>>>(x, coords4, sub4);
    fps_kernel<<<B_, FPS_T, 0, stream>>>(coords4, sub4);
    knn_kernel<N_/64,    N_   ><<<B_*M_/4, 256, 0, stream>>>(coords4, sub4, idx1);
    knn_kernel<SUBP_/64, SUBP_><<<B_*M_/4, 256, 0, stream>>>(sub4,    sub4, idx2);
    layer1_kernel<<<B_*M_, 128, 0, stream>>>(coords4, sub4, idx1, W1, b1, f1);
    layer2_kernel<<<B_*M_,  64, 0, stream>>>(sub4, f1, idx2, W2, b2, f2);
    pool_kernel<<<B_*OUT_, 256, 0, stream>>>(f2, out);
}

// Round 7
// 2361.230 us; speedup vs baseline: 1.0542x; 1.0542x over previous
//
#include <hip/hip_runtime.h>

#define B_    8
#define N_    8192
#define M_    2000
#define K_    16
#define C1_   128
#define C2_   256
#define OUT_  100
#define SUBP_ 2048   // padded per-batch pitch for subsampled points (KNN2 candidates)

// ---------------------------------------------------------------- prep: coords -> float4(x,y,z,|p|^2); pad sub4 sentinels
__global__ __launch_bounds__(256) void prep_kernel(const float* __restrict__ x,
                                                   float4* __restrict__ coords4,
                                                   float4* __restrict__ sub4) {
    int i = blockIdx.x * 256 + threadIdx.x;
    if (i < B_ * N_) {
        float xx = x[i*3+0], yy = x[i*3+1], zz = x[i*3+2];
        float ss = fmaf(zz, zz, fmaf(yy, yy, xx*xx));   // ((x^2+y^2)+z^2)
        coords4[i] = make_float4(xx, yy, zz, ss);
    }
    if (i < B_ * (SUBP_ - M_)) {   // sentinel pads: huge distance, never selected
        int b = i / (SUBP_ - M_), j = i % (SUBP_ - M_);
        sub4[b*SUBP_ + M_ + j] = make_float4(1e15f, 1e15f, 1e15f, 3e30f);
    }
}

// ---------------------------------------------------------------- FPS v7: compiler-packed float2 inner loop (no inline asm)
// v6 post-mortem: inline-asm v_pk_* with "v" pair constraints defeated regalloc ->
// ~429 insts/wave/iter (mov shuffles), same as scalar v2. gfx950 ISel selects
// v_pk_{add,mul,fma}_f32 natively from <2 x float> IR, so v7 expresses the SAME
// packed math at source level (ext_vector ops + __builtin_elementwise_{fma,min})
// and lets the compiler allocate registers. Bit-exact per half: pk rounding ==
// scalar, a-b exact, same fmaf association as reference FPS.
// Shell unchanged from v6: 512T (2 waves/SIMD for tail hiding), 8 pairs/thread,
// incremental strict-> argmax (ascending orig idx scan -> ref tie semantics).
// R6: resubmitted unchanged — previous bench died on container acquisition
// ("MI355X container failed twice"), no kernel signal.
#define FPS_T 512
#define FPS_PP 8    // float2 point-pairs per thread: 8 pairs = 16 points

typedef float v2f __attribute__((ext_vector_type(2)));

__device__ __forceinline__ unsigned long long umax64(unsigned long long a, unsigned long long b) {
    return a > b ? a : b;
}

// one stage of wave-max on a u64 key via DPP on both halves (identity 0: keys are non-negative)
template<int CTRL>
__device__ __forceinline__ unsigned long long dpp_max_u64(unsigned long long v) {
    int lo = __builtin_amdgcn_update_dpp(0, (int)(unsigned)(v & 0xFFFFFFFFull), CTRL, 0xF, 0xF, true);
    int hi = __builtin_amdgcn_update_dpp(0, (int)(v >> 32),                     CTRL, 0xF, 0xF, true);
    unsigned long long o = ((unsigned long long)(unsigned)hi << 32) | (unsigned)lo;
    return umax64(v, o);
}

__global__ __launch_bounds__(FPS_T, 1) void fps_kernel(const float4* __restrict__ coords4,
                                                       float4* __restrict__ sub4) {
    int b = blockIdx.x;
    int t = threadIdx.x;
    int w = t >> 6, lane = t & 63;
    const float4* C = coords4 + b * N_;

    __shared__ float4 Clds[N_];                              // 128 KB coords mirror (winner broadcast)
    __shared__ __align__(16) unsigned long long wkey[2][8];  // per-wave max keys, parity double-buffered

    v2f px_[FPS_PP], py_[FPS_PP], pz_[FPS_PP], mind[FPS_PP];
    unsigned inva_[FPS_PP], invb_[FPS_PP];
#pragma unroll
    for (int j = 0; j < FPS_PP; ++j) {
        int ia = t + (2*j)*FPS_T, ic = t + (2*j+1)*FPS_T;    // ascending orig idx in scan order
        float4 pa = C[ia], pb = C[ic];
        Clds[ia] = pa; Clds[ic] = pb;
        px_[j] = (v2f){pa.x, pb.x};
        py_[j] = (v2f){pa.y, pb.y};
        pz_[j] = (v2f){pa.z, pb.z};
        mind[j] = (v2f){1e30f, 1e30f};
        inva_[j] = 0xFFFFFFFFu - (unsigned)ia;               // tie -> smaller orig idx == larger inv
        invb_[j] = 0xFFFFFFFFu - (unsigned)ic;
    }
    float4 P0 = C[0];                                        // first pick = original index 0
    if (t == 0) sub4[b*SUBP_] = P0;
    v2f Px2 = (v2f){P0.x, P0.x};
    v2f Py2 = (v2f){P0.y, P0.y};
    v2f Pz2 = (v2f){P0.z, P0.z};
    __syncthreads();

    for (int i = 1; i < M_; ++i) {
        float runA = -3.4e38f, runB = -3.4e38f;
        unsigned ibA = 0u, ibB = 0u;
#pragma unroll
        for (int j = 0; j < FPS_PP; ++j) {
            v2f dx = px_[j] - Px2;                           // v_pk_add_f32 (neg modifier), exact
            v2f dy = py_[j] - Py2;
            v2f dz = pz_[j] - Pz2;
            v2f d2 = __builtin_elementwise_fma(dz, dz,
                      __builtin_elementwise_fma(dy, dy, dx*dx));   // matches ref association
            v2f m  = __builtin_elementwise_min(mind[j], d2);
            mind[j] = m;
            ibA = (m.x > runA) ? inva_[j] : ibA;             // strict >: earliest max kept (= ref tie)
            runA = fmaxf(runA, m.x);
            ibB = (m.y > runB) ? invb_[j] : ibB;
            runB = fmaxf(runB, m.y);
        }
        float runmax = fmaxf(runA, runB);
        // combine halves: equal values -> larger inv (smaller orig idx)
        unsigned ib = (runB > runA) ? ibB : ((runB == runA) ? (ibA > ibB ? ibA : ibB) : ibA);
        unsigned long long best = ((unsigned long long)__float_as_uint(runmax) << 32)
                                | (unsigned long long)ib;
        // wave max into lane 63: row_shr 1/2/4/8 then row_bcast 15/31 (all VALU)
        best = dpp_max_u64<0x111>(best);
        best = dpp_max_u64<0x112>(best);
        best = dpp_max_u64<0x114>(best);
        best = dpp_max_u64<0x118>(best);
        best = dpp_max_u64<0x142>(best);
        best = dpp_max_u64<0x143>(best);
        if (lane == 63) wkey[i & 1][w] = best;
        __syncthreads();
        const ulonglong2* wk2 = (const ulonglong2*)wkey[i & 1];
        ulonglong2 q0 = wk2[0], q1 = wk2[1], q2 = wk2[2], q3 = wk2[3];
        unsigned long long gk = umax64(umax64(umax64(q0.x, q0.y), umax64(q1.x, q1.y)),
                                       umax64(umax64(q2.x, q2.y), umax64(q3.x, q3.y)));
        int last = (int)(0xFFFFFFFFu - (unsigned)(gk & 0xFFFFFFFFull));
        float4 P4 = Clds[last];                              // broadcast LDS read (w = |p|^2 intact)
        Px2 = (v2f){P4.x, P4.x};
        Py2 = (v2f){P4.y, P4.y};
        Pz2 = (v2f){P4.z, P4.z};
        if (t == 0) sub4[b*SUBP_ + i] = P4;
    }
}

// ---------------------------------------------------------------- KNN: 1 wave per query, exact top-16 (set semantics)
// Pass 1: branchless lane-local sorted-16 of values only (15 CE bubble per candidate).
// Merge:  k-way merge of 64 sorted heads -> T = exact 16th smallest distance.
// Pass 2: ballot-collect indices with d<T, then earliest-index ties d==T (matches lax.top_k stability).
template<int NCH, int PITCH>
__global__ __launch_bounds__(256) void knn_kernel(const float4* __restrict__ cand,
                                                  const float4* __restrict__ qarr,
                                                  int* __restrict__ outIdx) {
    int lane = threadIdx.x & 63;
    int q = blockIdx.x * 4 + (threadIdx.x >> 6);
    int b = q / M_, m = q % M_;
    const float4* Cb = cand + b * PITCH;
    float4 Q = qarr[b * SUBP_ + m];

    float v[16];
#pragma unroll
    for (int tt = 0; tt < 16; ++tt) v[tt] = 3.4e38f;

#pragma unroll 2
    for (int j = 0; j < NCH; ++j) {
        float4 c = Cb[j*64 + lane];
        float dot = fmaf(c.z, Q.z, fmaf(c.y, Q.y, c.x * Q.x));
        float d = fmaf(-2.0f, dot, Q.w + c.w);   // == (qq+ss) - 2*dot, single rounding
        v[15] = fminf(v[15], d);
#pragma unroll
        for (int tt = 15; tt >= 1; --tt) {       // restore sortedness: bubble toward 0
            float lo = fminf(v[tt-1], v[tt]);
            float hi = fmaxf(v[tt-1], v[tt]);
            v[tt-1] = lo; v[tt] = hi;
        }
    }

    float T = 0.0f;
    for (int r = 0; r < 16; ++r) {               // extract global min 16 times (one entry per round)
        float g = v[0];
#pragma unroll
        for (int s = 1; s < 64; s <<= 1) g = fminf(g, __shfl_xor(g, s, 64));
        unsigned long long mk = __ballot(v[0] == g);
        int fl = __ffsll(mk) - 1;                // exactly one lane consumes (value ties resolved)
        if (lane == fl) {
#pragma unroll
            for (int tt = 0; tt < 15; ++tt) v[tt] = v[tt+1];
            v[15] = 3.4e38f;
        }
        T = g;
    }

    unsigned long long mlt = (1ull << lane) - 1ull;
    int base = q * K_;
    int cnt = 0;
    for (int j = 0; j < NCH; ++j) {              // all strictly-closer candidates (<= 15 of them)
        float4 c = Cb[j*64 + lane];
        float dot = fmaf(c.z, Q.z, fmaf(c.y, Q.y, c.x * Q.x));
        float d = fmaf(-2.0f, dot, Q.w + c.w);
        bool lt = d < T;
        unsigned long long m1 = __ballot(lt);
        if (lt) outIdx[base + cnt + __popcll(m1 & mlt)] = j*64 + lane;
        cnt += __popcll(m1);
    }
    int rem = K_ - cnt;                          // >= 1 (T itself); fill with earliest-index ties
    for (int j = 0; j < NCH && rem > 0; ++j) {
        float4 c = Cb[j*64 + lane];
        float dot = fmaf(c.z, Q.z, fmaf(c.y, Q.y, c.x * Q.x));
        float d = fmaf(-2.0f, dot, Q.w + c.w);
        bool eq = (d == T);
        unsigned long long m2 = __ballot(eq);
        int bef = __popcll(m2 & mlt);
        if (eq && bef < rem) outIdx[base + cnt + bef] = j*64 + lane;
        int take = __popcll(m2); if (take > rem) take = rem;
        cnt += take; rem -= take;
    }
}

// ---------------------------------------------------------------- layer 1: feats=[rel(3), ngh(3)] x W1[6,128], relu, max over k
__global__ __launch_bounds__(128) void layer1_kernel(const float4* __restrict__ coords4,
        const float4* __restrict__ sub4, const int* __restrict__ idx1,
        const float* __restrict__ W1, const float* __restrict__ b1,
        float* __restrict__ f1) {
    int q = blockIdx.x;
    int b = q / M_, m = q % M_;
    int c = threadIdx.x;
    __shared__ float4 ngh[K_];
    if (c < K_) ngh[c] = coords4[b*N_ + idx1[q*K_ + c]];
    __syncthreads();
    float4 Q = sub4[b*SUBP_ + m];
    float w0 = W1[c],        w1 = W1[C1_ + c],   w2 = W1[2*C1_ + c];
    float w3 = W1[3*C1_ + c], w4 = W1[4*C1_ + c], w5 = W1[5*C1_ + c];
    float bias = b1[c];
    float mx = -3.4e38f;
#pragma unroll
    for (int k = 0; k < K_; ++k) {
        float4 n = ngh[k];
        float rx = n.x - Q.x, ry = n.y - Q.y, rz = n.z - Q.z;
        float s = rx*w0; s = fmaf(ry,w1,s); s = fmaf(rz,w2,s);
        s = fmaf(n.x,w3,s); s = fmaf(n.y,w4,s); s = fmaf(n.z,w5,s);
        s += bias;
        s = fmaxf(s, 0.0f);
        mx = fmaxf(mx, s);
    }
    f1[q*C1_ + c] = mx;
}

// ---------------------------------------------------------------- layer 2: feats=[rel(3), fg(128)] x W2[131,256], relu, max over k
#define FPAD 20   // row pitch (floats): 16B-aligned rows, odd-ish banking for staging
__global__ __launch_bounds__(64) void layer2_kernel(const float4* __restrict__ sub4,
        const float* __restrict__ f1, const int* __restrict__ idx2,
        const float* __restrict__ W2, const float* __restrict__ b2,
        float* __restrict__ f2) {
    int q = blockIdx.x;
    int b = q / M_, m = q % M_;
    int t = threadIdx.x;
    __shared__ __align__(16) float feat[(3 + C1_) * FPAD];  // feat[f][k], k=0..15
    __shared__ int nidx[K_];
    float4 Q = sub4[b*SUBP_ + m];
    if (t < K_) {
        int ik = idx2[q*K_ + t];
        nidx[t] = ik;
        float4 n = sub4[b*SUBP_ + ik];
        feat[0*FPAD + t] = n.x - Q.x;
        feat[1*FPAD + t] = n.y - Q.y;
        feat[2*FPAD + t] = n.z - Q.z;
    }
    __syncthreads();
    for (int e = t; e < K_ * C1_; e += 64) {    // stage gathered f1 rows: feat[3+cc][k]
        int k = e >> 7, cc = e & 127;
        feat[(3 + cc)*FPAD + k] = f1[(b*M_ + nidx[k])*C1_ + cc];
    }
    __syncthreads();

    float acc[K_][4];
#pragma unroll
    for (int k = 0; k < K_; ++k) { acc[k][0]=0.f; acc[k][1]=0.f; acc[k][2]=0.f; acc[k][3]=0.f; }
    int c0 = t * 4;                              // 4 channels per thread, 64 threads = 256 ch
    for (int f = 0; f < 3 + C1_; ++f) {
        float4 w  = *(const float4*)(W2 + f*C2_ + c0);
        const float* row = feat + f*FPAD;
        float4 g0 = *(const float4*)(row + 0);
        float4 g1 = *(const float4*)(row + 4);
        float4 g2 = *(const float4*)(row + 8);
        float4 g3 = *(const float4*)(row + 12);
        float gk[16] = {g0.x,g0.y,g0.z,g0.w, g1.x,g1.y,g1.z,g1.w,
                        g2.x,g2.y,g2.z,g2.w, g3.x,g3.y,g3.z,g3.w};
#pragma unroll
        for (int k = 0; k < K_; ++k) {
            acc[k][0] = fmaf(gk[k], w.x, acc[k][0]);
            acc[k][1] = fmaf(gk[k], w.y, acc[k][1]);
            acc[k][2] = fmaf(gk[k], w.z, acc[k][2]);
            acc[k][3] = fmaf(gk[k], w.w, acc[k][3]);
        }
    }
    float4 bb = *(const float4*)(b2 + c0);
    float mx0 = -3.4e38f, mx1 = -3.4e38f, mx2 = -3.4e38f, mx3 = -3.4e38f;
#pragma unroll
    for (int k = 0; k < K_; ++k) {
        float h0 = fmaxf(acc[k][0] + bb.x, 0.0f);
        float h1 = fmaxf(acc[k][1] + bb.y, 0.0f);
        float h2 = fmaxf(acc[k][2] + bb.z, 0.0f);
        float h3 = fmaxf(acc[k][3] + bb.w, 0.0f);
        mx0 = fmaxf(mx0, h0); mx1 = fmaxf(mx1, h1);
        mx2 = fmaxf(mx2, h2); mx3 = fmaxf(mx3, h3);
    }
    *(float4*)(f2 + q*C2_ + c0) = make_float4(mx0, mx1, mx2, mx3);
}

// ---------------------------------------------------------------- fused adaptive max+avg pool
__global__ __launch_bounds__(256) void pool_kernel(const float* __restrict__ f2,
                                                   float* __restrict__ out) {
    int bo = blockIdx.x;
    int b = bo / OUT_, o = bo % OUT_;
    int c = threadIdx.x;
    float mx = -3.4e38f, sm = 0.0f;
#pragma unroll
    for (int w = 0; w < M_/OUT_; ++w) {
        float v = f2[(b*M_ + o*(M_/OUT_) + w)*C2_ + c];
        mx = fmaxf(mx, v);
        sm += v;
    }
    out[(b*C2_ + c)*OUT_ + o] = mx + sm / (float)(M_/OUT_);
}

// ---------------------------------------------------------------- launch
extern "C" void kernel_launch(void* const* d_in, const int* in_sizes, int n_in,
                              void* d_out, int out_size, void* d_ws, size_t ws_size,
                              hipStream_t stream) {
    const float* x  = (const float*)d_in[0];
    const float* W1 = (const float*)d_in[1];
    const float* b1 = (const float*)d_in[2];
    const float* W2 = (const float*)d_in[3];
    const float* b2 = (const float*)d_in[4];
    float* out = (float*)d_out;

    char* ws = (char*)d_ws;
    size_t off = 0;
    auto alloc = [&](size_t bytes) {
        void* p = ws + off;
        off += (bytes + 255) & ~(size_t)255;
        return p;
    };
    float4* coords4 = (float4*)alloc((size_t)B_*N_*sizeof(float4));     // 2 MB
    float4* sub4    = (float4*)alloc((size_t)B_*SUBP_*sizeof(float4));  // 256 KB
    int*    idx1    = (int*)  alloc((size_t)B_*M_*K_*sizeof(int));      // 2 MB
    int*    idx2    = (int*)  alloc((size_t)B_*M_*K_*sizeof(int));      // 2 MB
    float*  f1      = (float*)alloc((size_t)B_*M_*C1_*sizeof(float));   // 8 MB
    float*  f2      = (float*)alloc((size_t)B_*M_*C2_*sizeof(float));   // 16 MB

    prep_kernel<<<(B_*N_ + 255)/256, 256, 0, stream>>>(x, coords4, sub4);
    fps_kernel<<<B_, FPS_T, 0, stream>>>(coords4, sub4);
    knn_kernel<N_/64,    N_   ><<<B_*M_/4, 256, 0, stream>>>(coords4, sub4, idx1);
    knn_kernel<SUBP_/64, SUBP_><<<B_*M_/4, 256, 0, stream>>>(sub4,    sub4, idx2);
    layer1_kernel<<<B_*M_, 128, 0, stream>>>(coords4, sub4, idx1, W1, b1, f1);
    layer2_kernel<<<B_*M_,  64, 0, stream>>>(sub4, f1, idx2, W2, b2, f2);
    pool_kernel<<<B_*OUT_, 256, 0, stream>>>(f2, out);
}